// Round 1
// baseline (2901.892 us; speedup 1.0000x reference)
//
#include <hip/hip_runtime.h>

// SpikeMLP: 3x (GEMM + CLIF scan) in f64 for spike-exact agreement with the
// f64 numpy reference. Spikes are exact {0,1}; products w*s are exact, so the
// only rounding is f64 summation (~1e-13 vs reference) -- no spike flips.

#define TT 16  // timesteps

constexpr int KDIM = 2048;
constexpr int BM = 64;   // 4 batches x 16 timesteps
constexpr int BN = 64;
constexpr int BK = 32;
constexpr int LDSA = BM + 2;  // pad to 66: keeps 16B alignment, breaks bank conflicts
constexpr int LDSB = BN + 2;
constexpr int LDSC = BN + 2;

// in_pop_spikes [B=256][IN=2048][T=16] f32 -> X32 [(b*16+t)][IN] f32
__global__ __launch_bounds__(256)
void transpose_x(const float* __restrict__ in, float* __restrict__ out) {
  const int idx = blockIdx.x * 256 + threadIdx.x;   // (b, i) pair, i fastest
  const float4* src = reinterpret_cast<const float4*>(in) + (size_t)idx * 4;
  float4 v[4];
  v[0] = src[0]; v[1] = src[1]; v[2] = src[2]; v[3] = src[3];
  const float* f = reinterpret_cast<const float*>(v);
  const int b = idx >> 11;          // / 2048
  const int i = idx & 2047;
  float* dst = out + (size_t)b * TT * KDIM + i;
#pragma unroll
  for (int t = 0; t < TT; ++t) dst[(size_t)t * KDIM] = f[t];
}

// C[m][n] = sum_k A[m][k] * W[n][k]  (f64 accum), then fused bias + CLIF scan.
// m = b*16 + t; BM=64 covers 4 complete batches' time series, so the scan is
// done entirely in-block from the C tile staged in LDS.
// FINAL=false: out = spikes f32 [4096][N].  FINAL=true: out = mean f32 [256][N].
template<int N, bool FINAL>
__global__ __launch_bounds__(256)
void gemm_scan(const float* __restrict__ A,     // [4096][KDIM] f32 (values 0/1)
               const float* __restrict__ W,     // [N][KDIM] f32
               const float* __restrict__ bias,  // [N] f32
               float* __restrict__ out) {
  __shared__ union SM {
    struct { double a[BK][LDSA]; double b[BK][LDSB]; } ab;
    double c[BM][LDSC];
  } sm;

  const int tid = threadIdx.x;
  const int tx = tid & 15;   // 0..15  (n groups, strided by 16)
  const int ty = tid >> 4;   // 0..15  (m groups of 4)
  const int n0 = blockIdx.x * BN;
  const int m0 = blockIdx.y * BM;

  // staging: each thread loads one float4 from 2 rows of A and 2 rows of W
  const int sr = tid >> 3;   // 0..31 (row within tile)
  const int sc = tid & 7;    // 0..7  (float4 column group: 8*4 = 32 = BK)

  const float* Arow0 = A + (size_t)(m0 + sr) * KDIM + sc * 4;
  const float* Arow1 = Arow0 + (size_t)32 * KDIM;
  const float* Wrow0 = W + (size_t)(n0 + sr) * KDIM + sc * 4;
  const float* Wrow1 = Wrow0 + (size_t)32 * KDIM;

  double acc[4][4] = {};

  for (int k0 = 0; k0 < KDIM; k0 += BK) {
    const float4 a0 = *reinterpret_cast<const float4*>(Arow0 + k0);
    const float4 a1 = *reinterpret_cast<const float4*>(Arow1 + k0);
    const float4 w0 = *reinterpret_cast<const float4*>(Wrow0 + k0);
    const float4 w1 = *reinterpret_cast<const float4*>(Wrow1 + k0);
    __syncthreads();   // previous tile's LDS reads complete
    sm.ab.a[sc * 4 + 0][sr]      = (double)a0.x;
    sm.ab.a[sc * 4 + 1][sr]      = (double)a0.y;
    sm.ab.a[sc * 4 + 2][sr]      = (double)a0.z;
    sm.ab.a[sc * 4 + 3][sr]      = (double)a0.w;
    sm.ab.a[sc * 4 + 0][sr + 32] = (double)a1.x;
    sm.ab.a[sc * 4 + 1][sr + 32] = (double)a1.y;
    sm.ab.a[sc * 4 + 2][sr + 32] = (double)a1.z;
    sm.ab.a[sc * 4 + 3][sr + 32] = (double)a1.w;
    sm.ab.b[sc * 4 + 0][sr]      = (double)w0.x;
    sm.ab.b[sc * 4 + 1][sr]      = (double)w0.y;
    sm.ab.b[sc * 4 + 2][sr]      = (double)w0.z;
    sm.ab.b[sc * 4 + 3][sr]      = (double)w0.w;
    sm.ab.b[sc * 4 + 0][sr + 32] = (double)w1.x;
    sm.ab.b[sc * 4 + 1][sr + 32] = (double)w1.y;
    sm.ab.b[sc * 4 + 2][sr + 32] = (double)w1.z;
    sm.ab.b[sc * 4 + 3][sr + 32] = (double)w1.w;
    __syncthreads();   // staging visible
#pragma unroll
    for (int k = 0; k < BK; ++k) {
      const double2 aa0 = *reinterpret_cast<const double2*>(&sm.ab.a[k][ty * 4]);
      const double2 aa1 = *reinterpret_cast<const double2*>(&sm.ab.a[k][ty * 4 + 2]);
      const double av[4] = {aa0.x, aa0.y, aa1.x, aa1.y};
      const double bv[4] = {sm.ab.b[k][tx], sm.ab.b[k][tx + 16],
                            sm.ab.b[k][tx + 32], sm.ab.b[k][tx + 48]};
#pragma unroll
      for (int im = 0; im < 4; ++im)
#pragma unroll
        for (int in = 0; in < 4; ++in)
          acc[im][in] = fma(av[im], bv[in], acc[im][in]);
    }
  }

  __syncthreads();   // done reading ab; union region reused for C
#pragma unroll
  for (int im = 0; im < 4; ++im)
#pragma unroll
    for (int in = 0; in < 4; ++in)
      sm.c[ty * 4 + im][tx + in * 16] = acc[im][in];
  __syncthreads();

  // CLIF scan: one thread per (local batch, output neuron)
  const int nl = tid & 63;   // column within tile
  const int bl = tid >> 6;   // 0..3 local batch
  const double bv = (double)bias[n0 + nl];
  double c = 0.0, v = 0.0, s = 0.0, accum = 0.0;
#pragma unroll
  for (int t = 0; t < TT; ++t) {
    const double x = sm.c[bl * TT + t][nl] + bv;
    c = c * 0.5 + x;                    // NEURON_CDECAY = 0.5
    v = v * 0.75 * (1.0 - s) + c;      // NEURON_VDECAY = 0.75
    s = (v > 0.5) ? 1.0 : 0.0;         // NEURON_VTH = 0.5
    if (FINAL) {
      accum += s;
    } else {
      out[(size_t)(m0 + bl * TT + t) * N + (n0 + nl)] = (float)s;
    }
  }
  if (FINAL) {
    const int bg = (m0 >> 4) + bl;      // global batch index
    out[(size_t)bg * N + (n0 + nl)] = (float)(accum * 0.0625);  // mean over 16
  }
}

extern "C" void kernel_launch(void* const* d_in, const int* in_sizes, int n_in,
                              void* d_out, int out_size, void* d_ws, size_t ws_size,
                              hipStream_t stream) {
  const float* X  = (const float*)d_in[0];  // [256][2048][16]
  const float* W0 = (const float*)d_in[1];  // [2048][2048]
  const float* b0 = (const float*)d_in[2];  // [2048]
  const float* W1 = (const float*)d_in[3];  // [2048][2048]
  const float* b1 = (const float*)d_in[4];  // [2048]
  const float* Wo = (const float*)d_in[5];  // [1024][2048]
  const float* bo = (const float*)d_in[6];  // [1024]
  float* out = (float*)d_out;               // [256][1024]

  float* X32 = (float*)d_ws;                       // [4096][2048] f32 (33.5 MB)
  float* S0  = X32 + (size_t)4096 * 2048;          // [4096][2048] f32 (33.5 MB)
  float* S1  = X32;                                // reuse X32 (dead after GEMM0)

  transpose_x<<<2048, 256, 0, stream>>>(X, X32);
  gemm_scan<2048, false><<<dim3(2048 / BN, 4096 / BM), 256, 0, stream>>>(X32, W0, b0, S0);
  gemm_scan<2048, false><<<dim3(2048 / BN, 4096 / BM), 256, 0, stream>>>(S0, W1, b1, S1);
  gemm_scan<1024, true ><<<dim3(1024 / BN, 4096 / BM), 256, 0, stream>>>(S1, Wo, bo, out);
}

// Round 3
// 1395.361 us; speedup vs baseline: 2.0797x; 2.0797x over previous
//
#include <hip/hip_runtime.h>

// SpikeMLP: 3x (f64-MFMA GEMM + fused CLIF scan).
// Correctness strategy: spikes are exact {0,1}; f32->f64 exact; f64 MFMA
// accumulation differs from the np f64 reference only at ~1e-15 relative,
// far below spike-flip scale (verified empirically in round 1: absmax 0.0).
// The f64 D-fragment layout is NOT assumed: it is decoded at runtime with two
// cheap MFMAs and the epilogue scatters through LDS at decoded coordinates.

#define TT 16
constexpr int KDIM = 2048;
constexpr int BM = 64;    // 4 batches x 16 timesteps
constexpr int BN = 128;   // 8 n-tiles of 16
constexpr int BK = 16;    // 4 k-quads per tile

typedef double f64x4 __attribute__((ext_vector_type(4)));

// in_pop_spikes [B=256][IN=2048][T=16] f32 -> X32 [(b*16+t)][IN] f32
__global__ __launch_bounds__(256)
void transpose_x(const float* __restrict__ in, float* __restrict__ out) {
  const int idx = blockIdx.x * 256 + threadIdx.x;   // (b, i) pair, i fastest
  const float4* src = reinterpret_cast<const float4*>(in) + (size_t)idx * 4;
  float4 v[4];
  v[0] = src[0]; v[1] = src[1]; v[2] = src[2]; v[3] = src[3];
  const float* f = reinterpret_cast<const float*>(v);
  const int b = idx >> 11;
  const int i = idx & 2047;
  float* dst = out + (size_t)b * TT * KDIM + i;
#pragma unroll
  for (int t = 0; t < TT; ++t) dst[(size_t)t * KDIM] = f[t];
}

// C[m][n] = sum_k A[m][k]*W[n][k] via v_mfma_f64_16x16x4, fused CLIF scan.
// Wave w owns C rows [w*16, w*16+16) = batch (m0/16 + w), all 16 timesteps.
// A/B fragment convention (documented CDNA dgemm): A[m][k] at lane m+16k,
// B[k][n] at lane n+16k. D layout is decoded at runtime (see below).
template<int N, bool FINAL>
__global__ __launch_bounds__(256, 3)
void gemm_scan(const float* __restrict__ A,     // [4096][KDIM] f32 (0/1)
               const float* __restrict__ W,     // [N][KDIM] f32
               const float* __restrict__ bias,  // [N] f32
               float* __restrict__ out) {
  __shared__ float a_sm[4 * 4 * 64];        // [q][wslot][lane] fragment-ordered
  __shared__ float b_sm[4 * 8 * 64];        // [q][jslot][lane]
  __shared__ double c_sm[4][16][66];        // per-wave C half-tile, padded

  const int tid = threadIdx.x;
  const int lane = tid & 63;
  const int w = tid >> 6;
  const int l15 = lane & 15;
  const int lg = lane >> 4;
  const int n0 = blockIdx.x * BN;
  const int m0 = blockIdx.y * BM;

  // A staging: thread -> row ar (0..63), k-quad qa
  const int ar = tid >> 2, qa = tid & 3;
  const float* Ap = A + (size_t)(m0 + ar) * KDIM + qa * 4;
  const int aw = ((qa << 2) + (ar >> 4)) * 64 + (ar & 15);

  // B staging: thread -> row br (0..127), k-half kh in {0,8}
  const int br = tid >> 1, kh = (tid & 1) * 8;
  const float* Wp = W + (size_t)(n0 + br) * KDIM + kh;
  const int bq = kh >> 2;
  const int bw0 = ((bq + 0) * 8 + (br >> 4)) * 64 + (br & 15);
  const int bw1 = ((bq + 1) * 8 + (br >> 4)) * 64 + (br & 15);

  f64x4 acc[8] = {};

  float4 af = *(const float4*)Ap;
  float4 bf0 = *(const float4*)Wp;
  float4 bf1 = *(const float4*)(Wp + 4);

  for (int k0 = 0; k0 < KDIM; k0 += BK) {
    __syncthreads();   // previous tile's LDS reads complete
    a_sm[aw]       = af.x;  a_sm[aw + 16]  = af.y;
    a_sm[aw + 32]  = af.z;  a_sm[aw + 48]  = af.w;
    b_sm[bw0]      = bf0.x; b_sm[bw0 + 16] = bf0.y;
    b_sm[bw0 + 32] = bf0.z; b_sm[bw0 + 48] = bf0.w;
    b_sm[bw1]      = bf1.x; b_sm[bw1 + 16] = bf1.y;
    b_sm[bw1 + 32] = bf1.z; b_sm[bw1 + 48] = bf1.w;
    __syncthreads();   // staging visible
    if (k0 + BK < KDIM) {   // prefetch next tile; hides under MFMA
      af  = *(const float4*)(Ap + k0 + BK);
      bf0 = *(const float4*)(Wp + k0 + BK);
      bf1 = *(const float4*)(Wp + k0 + BK + 4);
    }
#pragma unroll
    for (int q = 0; q < 4; ++q) {
      const double av = (double)a_sm[((q << 2) + w) * 64 + lane];
#pragma unroll
      for (int j = 0; j < 8; ++j) {
        const double bv = (double)b_sm[((q << 3) + j) * 64 + lane];
        acc[j] = __builtin_amdgcn_mfma_f64_16x16x4f64(av, bv, acc[j], 0, 0, 0);
      }
    }
  }

  // --- Decode the D layout at runtime (2 MFMAs, negligible). ---
  // drow: A[m][0]=m, B[0][n]=1  => slot value = its D-row.
  // dcol: A[m][0]=1, B[0][n]=n  => slot value = its D-col.
  // Robust to any D bijection AND to A<->B operand-order confusion (a swap
  // transposes main GEMM and decode identically, so coordinates cancel).
  const f64x4 dz = {0.0, 0.0, 0.0, 0.0};
  const double dm = (lg == 0) ? (double)l15 : 0.0;
  const double d1 = (lg == 0) ? 1.0 : 0.0;
  const f64x4 drow = __builtin_amdgcn_mfma_f64_16x16x4f64(dm, d1, dz, 0, 0, 0);
  const f64x4 dcol = __builtin_amdgcn_mfma_f64_16x16x4f64(d1, dm, dz, 0, 0, 0);
  int rdec[4], cdec[4];
#pragma unroll
  for (int i = 0; i < 4; ++i) { rdec[i] = (int)drow[i]; cdec[i] = (int)dcol[i]; }

  // --- Epilogue in two 64-column halves through per-wave LDS C tile. ---
#pragma unroll
  for (int h = 0; h < 2; ++h) {
#pragma unroll
    for (int jj = 0; jj < 4; ++jj)
#pragma unroll
      for (int i = 0; i < 4; ++i)
        c_sm[w][rdec[i]][jj * 16 + cdec[i]] = acc[h * 4 + jj][i];
    __syncthreads();

    const int col = h * 64 + lane;            // 0..127 within BN
    const double bj = (double)bias[n0 + col];
    double cc = 0.0, vv = 0.0, ss = 0.0;
    if (!FINAL) {
#pragma unroll
      for (int t = 0; t < TT; ++t) {
        const double x = c_sm[w][t][lane] + bj;
        cc = cc * 0.5 + x;                    // NEURON_CDECAY
        vv = vv * 0.75 * (1.0 - ss) + cc;     // NEURON_VDECAY, soft reset
        ss = (vv > 0.5) ? 1.0 : 0.0;          // NEURON_VTH
        out[(size_t)(m0 + w * 16 + t) * N + (n0 + col)] = (float)ss;
      }
    } else {
      float tot = 0.0f;
#pragma unroll
      for (int t = 0; t < TT; ++t) {
        const double x = c_sm[w][t][lane] + bj;
        cc = cc * 0.5 + x;
        vv = vv * 0.75 * (1.0 - ss) + cc;
        ss = (vv > 0.5) ? 1.0 : 0.0;
        tot += (float)ss;
      }
      out[(size_t)(m0 / TT + w) * N + (n0 + col)] = tot * 0.0625f;  // mean/16
    }
    __syncthreads();
  }
}

extern "C" void kernel_launch(void* const* d_in, const int* in_sizes, int n_in,
                              void* d_out, int out_size, void* d_ws, size_t ws_size,
                              hipStream_t stream) {
  const float* X  = (const float*)d_in[0];  // [256][2048][16]
  const float* W0 = (const float*)d_in[1];  // [2048][2048]
  const float* b0 = (const float*)d_in[2];
  const float* W1 = (const float*)d_in[3];  // [2048][2048]
  const float* b1 = (const float*)d_in[4];
  const float* Wo = (const float*)d_in[5];  // [1024][2048]
  const float* bo = (const float*)d_in[6];
  float* out = (float*)d_out;               // [256][1024]

  float* X32 = (float*)d_ws;                       // [4096][2048] f32
  float* S0  = X32 + (size_t)4096 * 2048;          // [4096][2048] f32
  float* S1  = X32;                                // reuse (dead after GEMM0)

  transpose_x<<<2048, 256, 0, stream>>>(X, X32);
  gemm_scan<2048, false><<<dim3(2048 / BN, 4096 / BM), 256, 0, stream>>>(X32, W0, b0, S0);
  gemm_scan<2048, false><<<dim3(2048 / BN, 4096 / BM), 256, 0, stream>>>(S0, W1, b1, S1);
  gemm_scan<1024, true ><<<dim3(1024 / BN, 4096 / BM), 256, 0, stream>>>(S1, Wo, bo, out);
}

// Round 4
// 345.397 us; speedup vs baseline: 8.4016x; 4.0399x over previous
//
#include <hip/hip_runtime.h>
#include <stdint.h>

// SpikeMLP via exact fixed-point i8 MFMA.
// w -> n = rint(w * 2^42), 5 signed 8-bit digits. Spikes are {0,1} i8.
// Per-limb i32 MFMA sums are exact; i64 Horner combine is exact; f64 scale
// by 2^-42 is exact. Only deviation vs the f64-np reference: 2^-43 weight
// quantization (RMS input error ~2e-12 -> ~1e-4 expected spike flips).
// Fragment-layout robustness: A and B staged with identical lane mapping, so
// any within-lane k-permutation cancels; C/D layout decoded at runtime with
// uniform-byte MFMAs (immune to slot permutations).

typedef int v4i __attribute__((ext_vector_type(4)));
typedef int v16i __attribute__((ext_vector_type(16)));

#define TT 16
constexpr int KD = 2048;
constexpr double SCALE = 4398046511104.0;   // 2^42

// ---------- weight -> 5 signed-digit i8 planes ----------
__global__ __launch_bounds__(256)
void prep_limbs(const float* __restrict__ W, int8_t* __restrict__ dst, int total) {
  const int i4 = (blockIdx.x * 256 + threadIdx.x) * 4;
  if (i4 >= total) return;
  const float4 wv = *reinterpret_cast<const float4*>(W + i4);
  long long n[4];
  n[0] = (long long)rint((double)wv.x * SCALE);
  n[1] = (long long)rint((double)wv.y * SCALE);
  n[2] = (long long)rint((double)wv.z * SCALE);
  n[3] = (long long)rint((double)wv.w * SCALE);
#pragma unroll
  for (int l = 0; l < 5; ++l) {
    char c[4];
#pragma unroll
    for (int e = 0; e < 4; ++e) {
      const int d = (int)((n[e] + 128) & 255) - 128;   // balanced digit
      c[e] = (char)d;
      n[e] = (n[e] - d) >> 8;
    }
    *reinterpret_cast<char4*>(dst + (size_t)l * total + i4) =
        make_char4(c[0], c[1], c[2], c[3]);
  }
}

// ---------- [B][IN][T] f32 -> [(b,t)][IN] i8 spikes ----------
__global__ __launch_bounds__(256)
void transpose_x_i8(const float* __restrict__ in, int8_t* __restrict__ out) {
  const int idx = blockIdx.x * 256 + threadIdx.x;       // (b, i), i fastest
  const float4* src = reinterpret_cast<const float4*>(in) + (size_t)idx * 4;
  float4 v[4];
  v[0] = src[0]; v[1] = src[1]; v[2] = src[2]; v[3] = src[3];
  const float* f = reinterpret_cast<const float*>(v);
  const int b = idx >> 11, i = idx & 2047;
  int8_t* dst = out + (size_t)b * TT * KD + i;
#pragma unroll
  for (int t = 0; t < TT; ++t) dst[(size_t)t * KD] = (int8_t)f[t];
}

static __device__ __forceinline__ v16i zero16() {
  v16i z;
#pragma unroll
  for (int i = 0; i < 16; ++i) z[i] = 0;
  return z;
}

// ---------- fused i8 GEMM (5 limbs) + CLIF scan ----------
// Block: BM=128 (8 batches), BN=64, 8 waves; wave w -> msub=w>>1 (M 32-tile),
// nsub=w&1 (N 32-tile). A-fragments direct from global; B limbs double-
// buffered in LDS (one barrier per K-tile).
template<int N, bool FINAL>
__global__ __launch_bounds__(512, 4)
void gemm_scan_i8(const int8_t* __restrict__ A,    // [4096][2048] spikes
                  const int8_t* __restrict__ WL,   // [5][N][2048] limbs
                  const float* __restrict__ bias,  // [N]
                  void* __restrict__ outp) {
  __shared__ union SM {
    int8_t b[2][5 * 64 * 32];     // 20 KB double-buffered B staging
    double c[8][32 * 33];         // 67.6 KB epilogue C tiles (per wave)
  } sm;

  const int tid = threadIdx.x;
  const int lane = tid & 63;
  const int w = tid >> 6;
  const int msub = w >> 1, nsub = w & 1;
  const int m0 = blockIdx.x * 128;
  const int n0 = blockIdx.y * 64;

  // A-fragment: row = m0+msub*32+(lane&31), k-group = lane>>5 (16 bytes)
  const int8_t* Ap = A + (size_t)(m0 + msub * 32 + (lane & 31)) * KD
                       + (lane >> 5) * 16;

  // B staging jobs (16 B each): job0 = all 512 threads (limbs 0..3),
  // job1 = threads 0..127 (limb 4). pos -> (row pos>>1, k-half (pos&1)*16).
  const int l0 = tid >> 7, pos0 = tid & 127;
  const int bn0 = pos0 >> 1, bk0 = (pos0 & 1) * 16;
  const int8_t* Bp0 = WL + (size_t)l0 * N * KD + (size_t)(n0 + bn0) * KD + bk0;
  const int boff0 = l0 * 2048 + bn0 * 32 + bk0;
  const int bn1 = tid >> 1, bk1 = (tid & 1) * 16;
  const int8_t* Bp1 = WL + (size_t)4 * N * KD + (size_t)(n0 + bn1) * KD + bk1;
  const int boff1 = 4 * 2048 + bn1 * 32 + bk1;

  // B-fragment read offset: row = nsub*32+(lane&31), k-group = lane>>5
  const int brd = (nsub * 32 + (lane & 31)) * 32 + (lane >> 5) * 16;

  v16i acc[5];
#pragma unroll
  for (int l = 0; l < 5; ++l) acc[l] = zero16();

  // prologue: stage tile 0 into buffer 0
  {
    const v4i pb0 = *(const v4i*)Bp0;
    v4i pb1;
    if (tid < 128) pb1 = *(const v4i*)Bp1;
    *(v4i*)(&sm.b[0][boff0]) = pb0;
    if (tid < 128) *(v4i*)(&sm.b[0][boff1]) = pb1;
  }
  __syncthreads();
  v4i af = *(const v4i*)Ap;   // A fragment, tile 0

  for (int t = 0; t < KD / 32; ++t) {
    const int cur = t & 1;
    v4i nb0, nb1, na;
    const bool more = (t + 1 < KD / 32);
    if (more) {   // prefetch tile t+1 (global); latency hides under MFMA
      nb0 = *(const v4i*)(Bp0 + (t + 1) * 32);
      if (tid < 128) nb1 = *(const v4i*)(Bp1 + (t + 1) * 32);
      na = *(const v4i*)(Ap + (t + 1) * 32);
    }
    const int8_t* bb = sm.b[cur];
#pragma unroll
    for (int l = 0; l < 5; ++l) {
      const v4i bf = *(const v4i*)(bb + l * 2048 + brd);
      acc[l] = __builtin_amdgcn_mfma_i32_32x32x32_i8(af, bf, acc[l], 0, 0, 0);
    }
    if (more) {
      *(v4i*)(&sm.b[cur ^ 1][boff0]) = nb0;
      if (tid < 128) *(v4i*)(&sm.b[cur ^ 1][boff1]) = nb1;
      af = na;
    }
    __syncthreads();   // one barrier per K-tile (dbuf)
  }

  // ---- decode D layout at runtime (uniform-byte MFMAs, permutation-immune)
  const int r31 = lane & 31;
  const int rep = r31 * 0x01010101;
  v4i rowv; rowv[0] = rep; rowv[1] = rep; rowv[2] = rep; rowv[3] = rep;
  v4i onev; onev[0] = 0x01010101; onev[1] = 0x01010101;
            onev[2] = 0x01010101; onev[3] = 0x01010101;
  const v16i drow = __builtin_amdgcn_mfma_i32_32x32x32_i8(rowv, onev, zero16(), 0, 0, 0);
  const v16i dcol = __builtin_amdgcn_mfma_i32_32x32x32_i8(onev, rowv, zero16(), 0, 0, 0);

  // ---- combine limbs exactly, scatter x (f64) into per-wave LDS tile ----
  __syncthreads();                 // staging buffers dead; reuse union as C
  double* cw = sm.c[w];
#pragma unroll
  for (int i = 0; i < 16; ++i) {
    long long ts = acc[4][i];
    ts = (ts << 8) + acc[3][i];
    ts = (ts << 8) + acc[2][i];
    ts = (ts << 8) + acc[1][i];
    ts = (ts << 8) + acc[0][i];
    const int r = drow[i] >> 5;    // D = 32*row
    const int c = dcol[i] >> 5;    // D = 32*col
    cw[r * 33 + c] = (double)ts * 0x1p-42;
  }
  __syncthreads();                 // cheap; guarantees scatter visible

  // ---- CLIF scan: lane -> (local batch bl = lane>>5, column col = lane&31)
  const int col = lane & 31;
  const int bl = lane >> 5;
  const double bj = (double)bias[n0 + nsub * 32 + col];
  const int gm = m0 + msub * 32 + bl * 16;    // global row of t=0
  double cc = 0.0, vv = 0.0, ss = 0.0;
  if (!FINAL) {
    int8_t* so = (int8_t*)outp;
#pragma unroll
    for (int t = 0; t < TT; ++t) {
      const double x = cw[(bl * 16 + t) * 33 + col] + bj;
      cc = cc * 0.5 + x;                      // NEURON_CDECAY
      vv = vv * 0.75 * (1.0 - ss) + cc;       // NEURON_VDECAY, soft reset
      ss = (vv > 0.5) ? 1.0 : 0.0;            // NEURON_VTH
      so[(size_t)(gm + t) * N + (n0 + nsub * 32 + col)] = (int8_t)ss;
    }
  } else {
    float tot = 0.0f;
#pragma unroll
    for (int t = 0; t < TT; ++t) {
      const double x = cw[(bl * 16 + t) * 33 + col] + bj;
      cc = cc * 0.5 + x;
      vv = vv * 0.75 * (1.0 - ss) + cc;
      ss = (vv > 0.5) ? 1.0 : 0.0;
      tot += (float)ss;
    }
    ((float*)outp)[(size_t)(gm / TT) * N + (n0 + nsub * 32 + col)] =
        tot * 0.0625f;                        // mean over 16 timesteps
  }
}

extern "C" void kernel_launch(void* const* d_in, const int* in_sizes, int n_in,
                              void* d_out, int out_size, void* d_ws, size_t ws_size,
                              hipStream_t stream) {
  const float* X  = (const float*)d_in[0];  // [256][2048][16]
  const float* W0 = (const float*)d_in[1];  // [2048][2048]
  const float* b0 = (const float*)d_in[2];
  const float* W1 = (const float*)d_in[3];  // [2048][2048]
  const float* b1 = (const float*)d_in[4];
  const float* Wo = (const float*)d_in[5];  // [1024][2048]
  const float* bo = (const float*)d_in[6];
  float* out = (float*)d_out;               // [256][1024]

  int8_t* base = (int8_t*)d_ws;
  int8_t* Xi8 = base;                                   // 8.39 MB
  int8_t* S0  = base + (size_t)8388608;                 // 8.39 MB
  int8_t* S1  = Xi8;                                    // reuse after layer 0
  int8_t* L0  = base + (size_t)16777216;                // 5x4 MB = 21 MB
  int8_t* L1  = base + (size_t)37748736;                // 21 MB
  int8_t* Lo  = base + (size_t)58720256;                // 10.5 MB

  prep_limbs<<<(2048 * 2048 / 4 + 255) / 256, 256, 0, stream>>>(W0, L0, 2048 * 2048);
  prep_limbs<<<(2048 * 2048 / 4 + 255) / 256, 256, 0, stream>>>(W1, L1, 2048 * 2048);
  prep_limbs<<<(1024 * 2048 / 4 + 255) / 256, 256, 0, stream>>>(Wo, Lo, 1024 * 2048);
  transpose_x_i8<<<2048, 256, 0, stream>>>(X, Xi8);

  gemm_scan_i8<2048, false><<<dim3(32, 32), 512, 0, stream>>>(Xi8, L0, b0, S0);
  gemm_scan_i8<2048, false><<<dim3(32, 32), 512, 0, stream>>>(S0, L1, b1, S1);
  gemm_scan_i8<1024, true ><<<dim3(32, 16), 512, 0, stream>>>(S1, Lo, bo, out);
}